// Round 2
// baseline (19745.036 us; speedup 1.0000x reference)
//
#include <hip/hip_runtime.h>
#include <hip/hip_bf16.h>
#include <hip/hip_cooperative_groups.h>
#include <cstdint>
#include <cstddef>

namespace cg = cooperative_groups;

typedef short short8 __attribute__((ext_vector_type(8)));
typedef float f32x4 __attribute__((ext_vector_type(4)));

#define TT 512
#define BB 64
#define DD 1024
#define LL 1024

// ---------------------------------------------------------------------------
// Prep 1: transpose + convert 4 gate weights [2048,1024] fp32 -> Wt[c][k] bf16,
// c = g*1024 + l, k contiguous. (Same as R1 — verified correct.)
// ---------------------------------------------------------------------------
__global__ __launch_bounds__(256) void transpose_w(
    const float* __restrict__ Wf, const float* __restrict__ Wi,
    const float* __restrict__ Wo, const float* __restrict__ Wg,
    __hip_bfloat16* __restrict__ Wt) {
  __shared__ float tile[32][33];
  const int g = blockIdx.z;
  const float* W = (g == 0) ? Wf : (g == 1) ? Wi : (g == 2) ? Wo : Wg;
  const int k0 = blockIdx.x * 32, l0 = blockIdx.y * 32;
  const int c = threadIdx.x & 31, r0 = threadIdx.x >> 5;
#pragma unroll
  for (int rr = 0; rr < 4; ++rr) {
    const int kk = r0 + rr * 8;
    tile[kk][c] = W[(size_t)(k0 + kk) * LL + (l0 + c)];
  }
  __syncthreads();
#pragma unroll
  for (int rr = 0; rr < 4; ++rr) {
    const int ll = r0 + rr * 8;
    Wt[((size_t)(g * LL + l0 + ll) << 11) + (k0 + c)] = __float2bfloat16(tile[c][ll]);
  }
}

// ---------------------------------------------------------------------------
// Prep 2: x fp32 -> bf16 (one float4 -> 4 bf16 per thread).
// ---------------------------------------------------------------------------
__global__ __launch_bounds__(256) void xconv(const float* __restrict__ x,
                                             __hip_bfloat16* __restrict__ xbf) {
  const size_t i = (size_t)blockIdx.x * 256 + threadIdx.x;  // vec4 index
  const float4 v = ((const float4*)x)[i];
  union { __hip_bfloat16 b[4]; uint2 u; } o;
  o.b[0] = __float2bfloat16(v.x);
  o.b[1] = __float2bfloat16(v.y);
  o.b[2] = __float2bfloat16(v.z);
  o.b[3] = __float2bfloat16(v.w);
  ((uint2*)xbf)[i] = o.u;
}

// ---------------------------------------------------------------------------
// Persistent cooperative LSTM. 256 blocks x 512 thr (8 waves), 1 block/CU.
// Block owns 16 gate-cols: C(j) = (j>>2)*1024 + blk*4 + (j&3), j in [0,16).
// Weights for all K=2048 live in LDS for the whole T loop (64 KB).
// Per step: 16 k-chunks of 128, staged bf16 via global_load_lds (16B DMA),
// double-buffered with raw s_barrier + s_waitcnt vmcnt(2) so the next chunk's
// DMA stays in flight across the barrier. XOR swizzle (16B-chunk granularity)
// keeps frag reads <=2-way bank conflicts while DMA dest stays lane-linear.
// Wave (kp=w>>2, bt=w&3): b-tile bt, k-half kp; 2 MFMA per chunk into 2 accs.
// Epilogue: 2-way cross-wave LDS reduction, fp32 gates + c-state (LDS),
// h -> out (fp32) + ping-pong hbuf (bf16); grid.sync per step.
// ---------------------------------------------------------------------------
__global__ __launch_bounds__(512, 1) void lstm_persist(
    const __hip_bfloat16* __restrict__ xbf, const __hip_bfloat16* __restrict__ Wt,
    const float* __restrict__ bfv, const float* __restrict__ biv,
    const float* __restrict__ bov, const float* __restrict__ bgv,
    float* __restrict__ out,
    __hip_bfloat16* __restrict__ hb0, __hip_bfloat16* __restrict__ hb1) {
  cg::grid_group grid = cg::this_grid();

  __shared__ __align__(16) __hip_bfloat16 Wlds[16 * 2048];      // 64 KB
  __shared__ __align__(16) __hip_bfloat16 zbuf[2][64 * 128];    // 2 x 16 KB
  __shared__ float gs[64][20];                                  // 5 KB
  __shared__ float cs[256];                                     // 1 KB

  const int tid = threadIdx.x;
  const int lane = tid & 63;
  const int w = tid >> 6;       // wave 0..7
  const int quad = lane >> 4;
  const int hc = lane & 15;
  const int bt = w & 3;         // b-tile
  const int kp = w >> 2;        // k-half
  const int blk = blockIdx.x;
  const int l0 = blk * 4;

  // ---- weights -> LDS (once), swizzled: pos(j,jj) = (j<<8) | (jj ^ j) ----
#pragma unroll
  for (int i = 0; i < 8; ++i) {
    const int q = i * 512 + tid;     // 16B-chunk id, 4096 total
    const int j = q >> 8;            // local col 0..15
    const int jj = q & 255;          // k 16B-chunk 0..255
    const int C = ((j >> 2) << 10) + l0 + (j & 3);
    const uint4 v = *(const uint4*)(Wt + ((size_t)C << 11) + jj * 8);
    *(uint4*)&Wlds[((j << 8) | (jj ^ j)) << 3] = v;
  }
  if (tid < 256) cs[tid] = 0.0f;
  float bF = 0.f, bI = 0.f, bO = 0.f, bG = 0.f;
  if (tid < 256) {
    const int li = tid & 3;
    bF = bfv[l0 + li]; bI = biv[l0 + li]; bO = bov[l0 + li]; bG = bgv[l0 + li];
  }
  __syncthreads();

  // staging maps: call i covers LDS 16B-chunks p = w*128 + i*64 + lane
  int sb[2], sk[2], dst_e[2];
#pragma unroll
  for (int i = 0; i < 2; ++i) {
    const int p = w * 128 + i * 64 + lane;
    sb[i] = p >> 4;                          // z row (batch)
    sk[i] = ((p & 15) ^ (sb[i] & 15)) * 8;   // element offset within 128-col chunk
    dst_e[i] = (w * 128 + i * 64) * 8;       // wave-uniform LDS element base
  }

  for (int t = 0; t < TT; ++t) {
    const __hip_bfloat16* rbuf = (t & 1) ? hb0 : hb1;  // h_{t-1} (t=0 -> zeroed hb1)
    __hip_bfloat16* wbuf = (t & 1) ? hb1 : hb0;        // h_t
    const __hip_bfloat16* xrow = xbf + ((size_t)t << 16);

    // prologue: issue chunk 0 (x part) into zbuf[0]
#pragma unroll
    for (int i = 0; i < 2; ++i) {
      __builtin_amdgcn_global_load_lds(
          (const __attribute__((address_space(1))) uint32_t*)(xrow + ((size_t)sb[i] << 10) + sk[i]),
          (__attribute__((address_space(3))) uint32_t*)&zbuf[0][dst_e[i]], 16, 0, 0);
    }

    f32x4 acc0 = {}, acc1 = {};
#pragma unroll
    for (int ch = 0; ch < 16; ++ch) {
      if (ch < 15) {
        const int nc = ch + 1;
        const __hip_bfloat16* base =
            (nc < 8) ? (xrow + (nc << 7)) : (rbuf + ((nc - 8) << 7));
#pragma unroll
        for (int i = 0; i < 2; ++i) {
          __builtin_amdgcn_global_load_lds(
              (const __attribute__((address_space(1))) uint32_t*)(base + ((size_t)sb[i] << 10) + sk[i]),
              (__attribute__((address_space(3))) uint32_t*)&zbuf[nc & 1][dst_e[i]], 16, 0, 0);
        }
        asm volatile("s_waitcnt vmcnt(2)" ::: "memory");  // drain ch, keep ch+1 in flight
      } else {
        asm volatile("s_waitcnt vmcnt(0)" ::: "memory");
      }
      asm volatile("s_barrier" ::: "memory");

      const __hip_bfloat16* zb = &zbuf[ch & 1][0];
      {  // k-step s=0: klocal = kp*64 + quad*8
        const int j = kp * 8 + quad;
        const int r = bt * 16 + hc;
        const short8 a = *(const short8*)(zb + (((r << 4) | (j ^ hc)) << 3));
        const int jj = (ch << 4) | j;
        const short8 b = *(const short8*)(Wlds + (((hc << 8) | (jj ^ hc)) << 3));
        acc0 = __builtin_amdgcn_mfma_f32_16x16x32_bf16(a, b, acc0, 0, 0, 0);
      }
      {  // k-step s=1: klocal = kp*64 + 32 + quad*8
        const int j = kp * 8 + 4 + quad;
        const int r = bt * 16 + hc;
        const short8 a = *(const short8*)(zb + (((r << 4) | (j ^ hc)) << 3));
        const int jj = (ch << 4) | j;
        const short8 b = *(const short8*)(Wlds + (((hc << 8) | (jj ^ hc)) << 3));
        acc1 = __builtin_amdgcn_mfma_f32_16x16x32_bf16(a, b, acc1, 0, 0, 0);
      }
      asm volatile("s_barrier" ::: "memory");
    }

    // ---- cross-wave (kp) reduction ----
    const f32x4 accs = acc0 + acc1;
    if (kp == 1) {
#pragma unroll
      for (int r = 0; r < 4; ++r) gs[bt * 16 + quad * 4 + r][hc] = accs[r];
    }
    __syncthreads();
    if (kp == 0) {
#pragma unroll
      for (int r = 0; r < 4; ++r) gs[bt * 16 + quad * 4 + r][hc] += accs[r];
    }
    __syncthreads();

    // ---- pointwise LSTM update (fp32), 256 threads: (b, li) ----
    if (tid < 256) {
      const int b = tid >> 2, li = tid & 3;
      const float fp = gs[b][0 + li] + bF;
      const float ip = gs[b][4 + li] + bI;
      const float op = gs[b][8 + li] + bO;
      const float gp = gs[b][12 + li] + bG;
      const float fs = 1.0f / (1.0f + __expf(-fp));
      const float is = 1.0f / (1.0f + __expf(-ip));
      const float os = 1.0f / (1.0f + __expf(-op));
      const float gv = tanhf(gp);
      const float cn = fs * cs[tid] + is * gv;
      cs[tid] = cn;
      const float h = os * tanhf(cn);
      out[(((size_t)t * BB + b) << 10) + l0 + li] = h;
      wbuf[((size_t)b << 10) + l0 + li] = __float2bfloat16(h);
    }
    grid.sync();
  }
}

// ---------------------------------------------------------------------------
extern "C" void kernel_launch(void* const* d_in, const int* in_sizes, int n_in,
                              void* d_out, int out_size, void* d_ws, size_t ws_size,
                              hipStream_t stream) {
  const float* x   = (const float*)d_in[0];
  const float* Wf  = (const float*)d_in[1];
  const float* bfv = (const float*)d_in[2];
  const float* Wi  = (const float*)d_in[3];
  const float* biv = (const float*)d_in[4];
  const float* Wo  = (const float*)d_in[5];
  const float* bov = (const float*)d_in[6];
  const float* Wg  = (const float*)d_in[7];
  const float* bgv = (const float*)d_in[8];
  float* out = (float*)d_out;

  // ws: Wt bf16 [4096][2048] (16 MB) | xbf bf16 [512*64*1024] (64 MB) | hb0,hb1
  __hip_bfloat16* Wt  = (__hip_bfloat16*)d_ws;
  __hip_bfloat16* xbf = Wt + (size_t)4096 * 2048;
  __hip_bfloat16* hb0 = xbf + (size_t)TT * BB * LL;
  __hip_bfloat16* hb1 = hb0 + (size_t)BB * LL;

  transpose_w<<<dim3(64, 32, 4), 256, 0, stream>>>(Wf, Wi, Wo, Wg, Wt);
  xconv<<<dim3((TT * BB * LL) / 4 / 256), 256, 0, stream>>>(x, xbf);
  hipMemsetAsync(hb0, 0, (size_t)2 * BB * LL * sizeof(__hip_bfloat16), stream);

  void* args[] = {(void*)&xbf, (void*)&Wt, (void*)&bfv, (void*)&biv,
                  (void*)&bov, (void*)&bgv, (void*)&out, (void*)&hb0, (void*)&hb1};
  hipLaunchCooperativeKernel((const void*)lstm_persist, dim3(256), dim3(512),
                             args, 0, stream);
}

// Round 3
// 9347.017 us; speedup vs baseline: 2.1124x; 2.1124x over previous
//
#include <hip/hip_runtime.h>
#include <hip/hip_bf16.h>
#include <cstdint>
#include <cstddef>

typedef short short8 __attribute__((ext_vector_type(8)));
typedef float f32x4 __attribute__((ext_vector_type(4)));

#define TT 512
#define BB 64
#define DD 1024
#define LL 1024

// ---------------------------------------------------------------------------
// Prep 1: transpose + convert 4 gate weights [2048,1024] fp32 -> Wt[c][k] bf16,
// c = g*1024 + l, k contiguous. (Verified R1/R2.)
// ---------------------------------------------------------------------------
__global__ __launch_bounds__(256) void transpose_w(
    const float* __restrict__ Wf, const float* __restrict__ Wi,
    const float* __restrict__ Wo, const float* __restrict__ Wg,
    __hip_bfloat16* __restrict__ Wt) {
  __shared__ float tile[32][33];
  const int g = blockIdx.z;
  const float* W = (g == 0) ? Wf : (g == 1) ? Wi : (g == 2) ? Wo : Wg;
  const int k0 = blockIdx.x * 32, l0 = blockIdx.y * 32;
  const int c = threadIdx.x & 31, r0 = threadIdx.x >> 5;
#pragma unroll
  for (int rr = 0; rr < 4; ++rr) {
    const int kk = r0 + rr * 8;
    tile[kk][c] = W[(size_t)(k0 + kk) * LL + (l0 + c)];
  }
  __syncthreads();
#pragma unroll
  for (int rr = 0; rr < 4; ++rr) {
    const int ll = r0 + rr * 8;
    Wt[((size_t)(g * LL + l0 + ll) << 11) + (k0 + c)] = __float2bfloat16(tile[c][ll]);
  }
}

// ---------------------------------------------------------------------------
// Prep 2: x fp32 -> bf16.
// ---------------------------------------------------------------------------
__global__ __launch_bounds__(256) void xconv(const float* __restrict__ x,
                                             __hip_bfloat16* __restrict__ xbf) {
  const size_t i = (size_t)blockIdx.x * 256 + threadIdx.x;
  const float4 v = ((const float4*)x)[i];
  union { __hip_bfloat16 b[4]; uint2 u; } o;
  o.b[0] = __float2bfloat16(v.x);
  o.b[1] = __float2bfloat16(v.y);
  o.b[2] = __float2bfloat16(v.z);
  o.b[3] = __float2bfloat16(v.w);
  ((uint2*)xbf)[i] = o.u;
}

// ---------------------------------------------------------------------------
// One LSTM step, graph-noded. 256 blocks x 512 thr (8 waves, 2/SIMD).
// Block owns latent slice of 4 -> 16 gate-cols: col(hc) = (hc>>2)*1024+l0+(hc&3).
// Wave (bt = w&3, kp = w>>2): b-tile bt (16 batches), K-half kp (1024).
//   kp=0 reads x_t (bf16), kp=1 reads h_{t-1} (bf16 ping-pong buffer).
// A/B fragments loaded DIRECTLY from global (16B dwordx4 per lane; a wave's
// 64 loads form 16 x 64B contiguous segments -> L1/L2 served). No LDS
// staging, no barriers in the main loop. Groups of 8 k-steps, depth-2
// software pipeline (~16 loads in flight per wave).
// Epilogue: 2-phase LDS reduction over kp, fp32 pointwise, c in global.
// ---------------------------------------------------------------------------
__global__ __launch_bounds__(512) void lstm_step2(
    const __hip_bfloat16* __restrict__ xbf, const __hip_bfloat16* __restrict__ Wt,
    const float* __restrict__ bfv, const float* __restrict__ biv,
    const float* __restrict__ bov, const float* __restrict__ bgv,
    float* __restrict__ cbuf, float* __restrict__ out,
    const __hip_bfloat16* __restrict__ hread,
    __hip_bfloat16* __restrict__ hwrite, int t) {
  __shared__ float gs[64][17];  // +1 pad: quads land on distinct banks

  const int tid = threadIdx.x;
  const int lane = tid & 63, w = tid >> 6;
  const int quad = lane >> 4, hc = lane & 15;
  const int bt = w & 3, kp = w >> 2;
  const int l0 = blockIdx.x * 4;

  // B: weight col for lane hc, k-window [kp*1024, kp*1024+1024)
  const int col = ((hc >> 2) << 10) + l0 + (hc & 3);
  const __hip_bfloat16* wb = Wt + ((size_t)col << 11) + (kp << 10) + quad * 8;
  // A: z row bt*16+hc, same k-window (kp=0 -> x_t, kp=1 -> h_{t-1})
  const __hip_bfloat16* za =
      ((kp == 0) ? (xbf + ((size_t)t << 16)) : hread) + (((bt << 4) + hc) << 10) + quad * 8;

  f32x4 acc = {};
  short8 Af[2][8], Bf[2][8];
#pragma unroll
  for (int i = 0; i < 8; ++i) {          // prologue: group 0
    Af[0][i] = *(const short8*)(za + i * 32);
    Bf[0][i] = *(const short8*)(wb + i * 32);
  }
#pragma unroll
  for (int g = 0; g < 4; ++g) {          // 4 groups x 8 k-steps = K/2 = 1024
    const int cur = g & 1, nxt = cur ^ 1;
    if (g < 3) {
#pragma unroll
      for (int i = 0; i < 8; ++i) {
        Af[nxt][i] = *(const short8*)(za + (g + 1) * 256 + i * 32);
        Bf[nxt][i] = *(const short8*)(wb + (g + 1) * 256 + i * 32);
      }
    }
#pragma unroll
    for (int i = 0; i < 8; ++i)
      acc = __builtin_amdgcn_mfma_f32_16x16x32_bf16(Af[cur][i], Bf[cur][i], acc, 0, 0, 0);
  }

  // ---- cross-wave (kp) reduction: C/D layout row=quad*4+r, col=hc ----
  if (kp == 1) {
#pragma unroll
    for (int r = 0; r < 4; ++r) gs[(bt << 4) + (quad << 2) + r][hc] = acc[r];
  }
  __syncthreads();
  if (kp == 0) {
#pragma unroll
    for (int r = 0; r < 4; ++r) gs[(bt << 4) + (quad << 2) + r][hc] += acc[r];
  }
  __syncthreads();

  // ---- pointwise LSTM update (fp32): thread -> (b, li) ----
  if (tid < 256) {
    const int b = tid >> 2, li = tid & 3;
    const int l = l0 + li;
    const float fp = gs[b][0 + li] + bfv[l];
    const float ip = gs[b][4 + li] + biv[l];
    const float op = gs[b][8 + li] + bov[l];
    const float gp = gs[b][12 + li] + bgv[l];
    const float fs = 1.0f / (1.0f + __expf(-fp));
    const float is = 1.0f / (1.0f + __expf(-ip));
    const float os = 1.0f / (1.0f + __expf(-op));
    const float gv = tanhf(gp);
    const size_t ci = ((size_t)b << 10) + l;
    const float cn = fs * cbuf[ci] + is * gv;
    cbuf[ci] = cn;
    const float h = os * tanhf(cn);
    out[(((size_t)t * BB + b) << 10) + l] = h;
    hwrite[ci] = __float2bfloat16(h);
  }
}

// ---------------------------------------------------------------------------
extern "C" void kernel_launch(void* const* d_in, const int* in_sizes, int n_in,
                              void* d_out, int out_size, void* d_ws, size_t ws_size,
                              hipStream_t stream) {
  const float* x   = (const float*)d_in[0];
  const float* Wf  = (const float*)d_in[1];
  const float* bfv = (const float*)d_in[2];
  const float* Wi  = (const float*)d_in[3];
  const float* biv = (const float*)d_in[4];
  const float* Wo  = (const float*)d_in[5];
  const float* bov = (const float*)d_in[6];
  const float* Wg  = (const float*)d_in[7];
  const float* bgv = (const float*)d_in[8];
  float* out = (float*)d_out;

  // ws: Wt bf16 [4096][2048] (16 MB) | xbf (64 MB) | hb0,hb1 (256 KB) | cbuf (256 KB)
  __hip_bfloat16* Wt  = (__hip_bfloat16*)d_ws;
  __hip_bfloat16* xbf = Wt + (size_t)4096 * 2048;
  __hip_bfloat16* hb0 = xbf + (size_t)TT * BB * LL;
  __hip_bfloat16* hb1 = hb0 + (size_t)BB * LL;
  float* cbuf = (float*)(hb1 + (size_t)BB * LL);

  transpose_w<<<dim3(64, 32, 4), 256, 0, stream>>>(Wf, Wi, Wo, Wg, Wt);
  xconv<<<dim3((TT * BB * LL) / 4 / 256), 256, 0, stream>>>(x, xbf);
  hipMemsetAsync(hb0, 0, (size_t)2 * BB * LL * sizeof(__hip_bfloat16), stream);
  hipMemsetAsync(cbuf, 0, (size_t)BB * LL * sizeof(float), stream);

  for (int t = 0; t < TT; ++t) {
    const __hip_bfloat16* hr = (t & 1) ? hb0 : hb1;  // t=0 reads zeroed hb1
    __hip_bfloat16* hw = (t & 1) ? hb1 : hb0;
    lstm_step2<<<256, 512, 0, stream>>>(xbf, Wt, bfv, biv, bov, bgv,
                                        cbuf, out, hr, hw, t);
  }
}